// Round 3
// baseline (633.673 us; speedup 1.0000x reference)
//
#include <hip/hip_runtime.h>
#include <hip/hip_bf16.h>
#include <stdint.h>

#define HH 512
#define BB 32
#define SSEQ 256
#define TVOC 50003
#define EPSF 1e-10f
#define EMSCALE 96.0f
// 255*ln(512) + 256*ln(96)
#define TOTLOG 2759.2459164008406f

typedef float f32x4 __attribute__((ext_vector_type(4)));
typedef int v8i __attribute__((ext_vector_type(8)));

__device__ __forceinline__ float wave_max(float v) {
#pragma unroll
  for (int off = 32; off; off >>= 1) v = fmaxf(v, __shfl_xor(v, off));
  return v;
}
__device__ __forceinline__ float wave_sum(float v) {
#pragma unroll
  for (int off = 32; off; off >>= 1) v += __shfl_xor(v, off);
  return v;
}

// ---------------------------------------------------------------- ws init
__global__ __launch_bounds__(512) void init_ws_kernel(float* ws) {
  if (threadIdx.x < 8) ws[threadIdx.x] = 0.0f;
  ws[8 + threadIdx.x] = 0.0f;
}

// ---------------------------------------------------------------- pi softmax
__global__ __launch_bounds__(512) void softmax_pi_kernel(
    const float* __restrict__ x, float* __restrict__ pi) {
  const int tid = threadIdx.x;
  const int wv = tid >> 6, ln = tid & 63;
  __shared__ float red[8];
  float v = x[tid];
  float m = wave_max(v);
  if (ln == 0) red[wv] = m;
  __syncthreads();
  float M = red[0];
#pragma unroll
  for (int i = 1; i < 8; ++i) M = fmaxf(M, red[i]);
  float e = __expf(v - M);
  float s = wave_sum(e);
  __syncthreads();
  if (ln == 0) red[wv] = s;
  __syncthreads();
  float S = 0.f;
#pragma unroll
  for (int i = 0; i < 8; ++i) S += red[i];
  pi[tid] = e / S;
}

// ---------------------------------------------------------------- A softmax + entropy
__global__ __launch_bounds__(512) void softmaxA_kernel(
    const float* __restrict__ tl, float* __restrict__ outA,
    float* __restrict__ ws_ent) {
  const int r = blockIdx.x, tid = threadIdx.x;
  const int wv = tid >> 6, ln = tid & 63;
  __shared__ float red[8];
  float v = tl[(size_t)r * HH + tid];
  float m = wave_max(v);
  if (ln == 0) red[wv] = m;
  __syncthreads();
  float M = red[0];
#pragma unroll
  for (int i = 1; i < 8; ++i) M = fmaxf(M, red[i]);
  float e = __expf(v - M);
  float s = wave_sum(e);
  __syncthreads();
  if (ln == 0) red[wv] = s;
  __syncthreads();
  float S = 0.f;
#pragma unroll
  for (int i = 0; i < 8; ++i) S += red[i];
  float p = e / S;
  outA[(size_t)r * HH + tid] = p;
  float ent = -p * __logf(p + EPSF);
  ent = wave_sum(ent);
  __syncthreads();
  if (ln == 0) red[wv] = ent;
  __syncthreads();
  if (tid == 0) {
    float tot = 0.f;
#pragma unroll
    for (int i = 0; i < 8; ++i) tot += red[i];
    atomicAdd(ws_ent, tot);
  }
}

// ---------------------------------------------------------------- partial column sums
__global__ __launch_bounds__(512) void colsum_partial_kernel(
    const float* __restrict__ outA, float* __restrict__ col) {
  const int j = threadIdx.x;
  const int i0 = blockIdx.x * 16;
  float s = 0.f;
#pragma unroll 4
  for (int i = i0; i < i0 + 16; ++i) s += outA[(size_t)i * HH + j];
  atomicAdd(&col[j], s);
}

// ---------------------------------------------------------------- B softmax + fused emission gather
__global__ __launch_bounds__(1024) void softmaxB_gather_kernel(
    const float* __restrict__ el, float* __restrict__ outB,
    const int* __restrict__ tok, __hip_bfloat16* __restrict__ ems) {
  const int r = blockIdx.x, tid = threadIdx.x;
  const float* x = el + (size_t)r * TVOC;
  float* yo = outB + (size_t)r * TVOC;
  const int mis = (int)(((16u - ((unsigned)(uintptr_t)x & 15u)) & 15u) >> 2);
  const int body = (TVOC - mis) >> 2;
  const int tailoff = mis + body * 4;

  float m = -1e30f, s = 0.f;
  auto upd = [&m, &s](float v) {
    if (v > m) { s = s * __expf(m - v) + 1.f; m = v; }
    else       { s += __expf(v - m); }
  };
  if (tid < mis) upd(x[tid]);
  const float4* x4 = (const float4*)(x + mis);
  for (int i = tid; i < body; i += 1024) {
    float4 v = x4[i];
    upd(v.x); upd(v.y); upd(v.z); upd(v.w);
  }
  for (int i = tailoff + tid; i < TVOC; i += 1024) upd(x[i]);

#pragma unroll
  for (int off = 32; off; off >>= 1) {
    float om = __shfl_down(m, off), os = __shfl_down(s, off);
    float nm = fmaxf(m, om);
    s = s * __expf(m - nm) + os * __expf(om - nm);
    m = nm;
  }
  __shared__ float sm[16], ssv[16];
  __shared__ float bM, biZ;
  if ((tid & 63) == 0) { sm[tid >> 6] = m; ssv[tid >> 6] = s; }
  __syncthreads();
  if (tid == 0) {
    float M = sm[0], S = ssv[0];
#pragma unroll
    for (int w = 1; w < 16; ++w) {
      float nm = fmaxf(M, sm[w]);
      S = S * __expf(M - nm) + ssv[w] * __expf(sm[w] - nm);
      M = nm;
    }
    bM = M; biZ = 1.f / S;
  }
  __syncthreads();
  const float M = bM, iZ = biZ;
  if (tid < mis) yo[tid] = __expf(x[tid] - M) * iZ;
  float4* y4 = (float4*)(yo + mis);
  for (int i = tid; i < body; i += 1024) {
    float4 v = x4[i];
    float4 o;
    o.x = __expf(v.x - M) * iZ;
    o.y = __expf(v.y - M) * iZ;
    o.z = __expf(v.z - M) * iZ;
    o.w = __expf(v.w - M) * iZ;
    y4[i] = o;
  }
  for (int i = tailoff + tid; i < TVOC; i += 1024)
    yo[i] = __expf(x[i] - M) * iZ;

  // fused gather: ems[s][j=r][b] = softmaxB[r][tok[b,s]] * EMSCALE
  const float gs = EMSCALE * iZ;
  for (int idx = tid; idx < BB * SSEQ; idx += 1024) {
    const int sq = idx >> 5, b = idx & 31;
    const int t = tok[b * SSEQ + sq];
    ems[((size_t)sq * HH + r) * BB + b] = __float2bfloat16(__expf(x[t] - M) * gs);
  }
}

// ---------------------------------------------------------------- forward scan
// 2 WGs x 512 threads (8 waves); WG h owns batches [h*16, h*16+16).
// Wave owns 64 j-rows (4 subtiles of 16). As = A*512 resident in VGPRs as fp8
// e4m3 K=128 A-fragments (MX op, trivial scales). alpha fp8 in LDS, dbuf,
// rows padded to 528 B. Emissions pre-scaled by EMSCALE -> per-step multiplier
// ~1: renorm only every 16 steps. Normal step: 1 barrier, 16 MFMA/wave,
// 8 ds_read_b128/wave (LDS traffic halved vs 16-wave version).
__global__ __launch_bounds__(512, 2) void scan_kernel(
    const float* __restrict__ d_pi, const float* __restrict__ d_A,
    const __hip_bfloat16* __restrict__ ems, float* __restrict__ ws_negll) {
  const int h = blockIdx.x;
  const int tid = threadIdx.x;
  const int lane = tid & 63;
  const int wave = tid >> 6;   // 0..7 ; wave owns j-tile [wave*64, wave*64+64)
  const int l15 = lane & 15;
  const int quad = lane >> 4;  // 0..3

  __shared__ __align__(16) unsigned char alpha[2][16][528];  // [buf][b][state(k)]
  __shared__ float wmax[8][17];
  __shared__ float wsum[8][17];
  __shared__ float ls[16];

  const unsigned short* emsu = (const unsigned short*)ems;

  // ---- resident A fragments: subtile n -> j = wave*64 + n*16 + l15
  //      chunk c, byte p of v8i <-> k = c*128 + quad*32 + p
  v8i aF[4][4];
#pragma unroll
  for (int n = 0; n < 4; ++n) {
    const int jg = wave * 64 + n * 16 + l15;
#pragma unroll
    for (int c = 0; c < 4; ++c) {
#pragma unroll
      for (int g = 0; g < 8; ++g) {
        const int k0 = c * 128 + quad * 32 + g * 4;
        const float v0 = d_A[(size_t)(k0 + 0) * HH + jg] * 512.0f;
        const float v1 = d_A[(size_t)(k0 + 1) * HH + jg] * 512.0f;
        const float v2 = d_A[(size_t)(k0 + 2) * HH + jg] * 512.0f;
        const float v3 = d_A[(size_t)(k0 + 3) * HH + jg] * 512.0f;
        int wrd = 0;
        wrd = __builtin_amdgcn_cvt_pk_fp8_f32(v0, v1, wrd, false);
        wrd = __builtin_amdgcn_cvt_pk_fp8_f32(v2, v3, wrd, true);
        aF[n][c][g] = wrd;
      }
    }
  }

  // ---- t = 0 init: each wave fills 2 batches, half-wave (32 lanes) per batch
  {
    const int b = wave * 2 + (lane >> 5);  // 0..15
    const int lh = lane & 31;
    const int j0 = lh * 16;
    float vals[16];
    float m = -1e30f;
#pragma unroll
    for (int u = 0; u < 16; ++u) {
      const float e = __bfloat162float(ems[(size_t)(j0 + u) * BB + h * 16 + b]);
      vals[u] = (d_pi[j0 + u] + EPSF) * e;
      m = fmaxf(m, vals[u]);
    }
#pragma unroll
    for (int off = 16; off; off >>= 1) m = fmaxf(m, __shfl_xor(m, off));
    if (lh == 0) ls[b] = __logf(m);
    const float r = 1.0f / m;
#pragma unroll
    for (int d = 0; d < 4; ++d) {
      int wrd = 0;
      wrd = __builtin_amdgcn_cvt_pk_fp8_f32(vals[d*4+0] * r, vals[d*4+1] * r, wrd, false);
      wrd = __builtin_amdgcn_cvt_pk_fp8_f32(vals[d*4+2] * r, vals[d*4+3] * r, wrd, true);
      *(unsigned int*)&alpha[0][b][j0 + d * 4] = (unsigned)wrd;
    }
  }
  __syncthreads();

  // ---- preload emissions for t=1
  unsigned short evr[4][4];
#pragma unroll
  for (int n = 0; n < 4; ++n)
#pragma unroll
    for (int rg = 0; rg < 4; ++rg) {
      const int j = wave * 64 + n * 16 + quad * 4 + rg;
      evr[n][rg] = emsu[((size_t)1 * HH + j) * BB + h * 16 + l15];
    }

#pragma unroll 1
  for (int t = 1; t < SSEQ; ++t) {
    const int cur = (t - 1) & 1, nxt = t & 1;

    // this step's emissions (loaded last iter)
    float ev[4][4];
#pragma unroll
    for (int n = 0; n < 4; ++n)
#pragma unroll
      for (int rg = 0; rg < 4; ++rg)
        ev[n][rg] = __uint_as_float((unsigned)evr[n][rg] << 16);

    // prefetch t+1 (single per-lane base + compile-time offsets)
    const int tp = (t + 1 < SSEQ) ? t + 1 : SSEQ - 1;
    const unsigned short* ep =
        emsu + ((size_t)tp * HH + wave * 64 + quad * 4) * BB + h * 16 + l15;
#pragma unroll
    for (int n = 0; n < 4; ++n)
#pragma unroll
      for (int rg = 0; rg < 4; ++rg)
        evr[n][rg] = ep[(n * 16 + rg) * BB];

    f32x4 acc[4] = {{0.f,0.f,0.f,0.f},{0.f,0.f,0.f,0.f},
                    {0.f,0.f,0.f,0.f},{0.f,0.f,0.f,0.f}};
#pragma unroll
    for (int c = 0; c < 4; ++c) {
      const unsigned char* ap = &alpha[cur][l15][c * 128 + quad * 32];
      const int4 lo = *(const int4*)ap;
      const int4 hi = *(const int4*)(ap + 16);
      v8i bf;
      bf[0] = lo.x; bf[1] = lo.y; bf[2] = lo.z; bf[3] = lo.w;
      bf[4] = hi.x; bf[5] = hi.y; bf[6] = hi.z; bf[7] = hi.w;
#pragma unroll
      for (int n = 0; n < 4; ++n)
        acc[n] = __builtin_amdgcn_mfma_scale_f32_16x16x128_f8f6f4(
            aF[n][c], bf, acc[n], 0, 0, 0, 0x7F7F7F7F, 0, 0x7F7F7F7F);
    }

    // D layout: col(b)=lane&15, row(j within subtile)=quad*4+reg
    float y[4][4];
#pragma unroll
    for (int n = 0; n < 4; ++n)
#pragma unroll
      for (int rg = 0; rg < 4; ++rg)
        y[n][rg] = acc[n][rg] * ev[n][rg];

    float r = 1.0f;
    if ((t & 15) == 0) {  // renorm: per-batch global max + log accounting
      float mm = -1e30f;
#pragma unroll
      for (int n = 0; n < 4; ++n)
#pragma unroll
        for (int rg = 0; rg < 4; ++rg) mm = fmaxf(mm, y[n][rg]);
      mm = fmaxf(mm, __shfl_xor(mm, 16));
      mm = fmaxf(mm, __shfl_xor(mm, 32));
      if (lane < 16) wmax[wave][lane] = mm;
      __syncthreads();
      float m = wmax[0][l15];
#pragma unroll
      for (int w = 1; w < 8; ++w) m = fmaxf(m, wmax[w][l15]);
      r = 1.0f / m;
      if (tid < 16) ls[tid] += __logf(m);
    }

#pragma unroll
    for (int n = 0; n < 4; ++n) {
      int d = 0;
      d = __builtin_amdgcn_cvt_pk_fp8_f32(y[n][0] * r, y[n][1] * r, d, false);
      d = __builtin_amdgcn_cvt_pk_fp8_f32(y[n][2] * r, y[n][3] * r, d, true);
      *(unsigned int*)&alpha[nxt][l15][wave * 64 + n * 16 + quad * 4] = (unsigned)d;
    }
    if (t == SSEQ - 1) {
      float s = 0.f;
#pragma unroll
      for (int n = 0; n < 4; ++n)
        s += y[n][0] + y[n][1] + y[n][2] + y[n][3];
      s *= r;
      s += __shfl_xor(s, 16);
      s += __shfl_xor(s, 32);
      if (lane < 16) wsum[wave][lane] = s;
    }
    __syncthreads();
  }

  if (wave == 0 && lane < 16) {
    float s = 0.f;
#pragma unroll
    for (int w = 0; w < 8; ++w) s += wsum[w][lane];
    const float LL = __logf(s) + ls[lane] - TOTLOG;
    atomicAdd(ws_negll, -LL * (1.0f / 32.0f));
  }
}

// ---------------------------------------------------------------- finalize loss
__global__ __launch_bounds__(512) void finalize_kernel(
    const float* __restrict__ ws, const float* __restrict__ col,
    const float* __restrict__ thr, float* __restrict__ out_loss) {
  const int j = threadIdx.x;
  float v = fmaxf(thr[0] - col[j], 0.f);
  v = wave_sum(v);
  __shared__ float red[8];
  if ((j & 63) == 0) red[j >> 6] = v;
  __syncthreads();
  if (j == 0) {
    float creg = 0.f;
#pragma unroll
    for (int i = 0; i < 8; ++i) creg += red[i];
    out_loss[0] = ws[1] + ws[0] * (0.1f / 512.0f) + creg;
  }
}

// ----------------------------------------------------------------
extern "C" void kernel_launch(void* const* d_in, const int* in_sizes, int n_in,
                              void* d_out, int out_size, void* d_ws, size_t ws_size,
                              hipStream_t stream) {
  const int*   tok    = (const int*)d_in[0];
  const float* initl  = (const float*)d_in[1];
  const float* transl = (const float*)d_in[2];
  const float* eml    = (const float*)d_in[3];
  const float* thr    = (const float*)d_in[4];

  float* out      = (float*)d_out;
  float* out_pi   = out;
  float* out_A    = out + HH;
  float* out_B    = out + HH + (size_t)HH * HH;
  float* out_loss = out + HH + (size_t)HH * HH + (size_t)HH * TVOC;

  float* wsf = (float*)d_ws;           // [0..8) scalars, [8..520) col sums
  float* col = wsf + 8;
  __hip_bfloat16* ems = (__hip_bfloat16*)((char*)d_ws + 4096);  // bf16 [S][H][B]

  init_ws_kernel<<<1, 512, 0, stream>>>(wsf);
  softmax_pi_kernel<<<1, 512, 0, stream>>>(initl, out_pi);
  softmaxA_kernel<<<512, 512, 0, stream>>>(transl, out_A, wsf + 0);
  colsum_partial_kernel<<<32, 512, 0, stream>>>(out_A, col);
  softmaxB_gather_kernel<<<512, 1024, 0, stream>>>(eml, out_B, tok, ems);
  scan_kernel<<<2, 512, 0, stream>>>(out_pi, out_A, ems, wsf + 1);
  finalize_kernel<<<1, 512, 0, stream>>>(wsf, col, thr, out_loss);
}